// Round 8
// baseline (429.913 us; speedup 1.0000x reference)
//
#include <hip/hip_runtime.h>
#include <hip/hip_fp16.h>

#define NN 100000
#define NE 1600000
#define F 64
#define NG 64
#define BN_EPS 1e-5f
#define SCAN_B 1024
#define NBLK ((NN + SCAN_B - 1) / SCAN_B)   // 98
#define NCH 8
#define NPC (NN / NCH)                       // 12500 nodes per chunk
#define EPB 1024
#define NBE ((NE + EPB - 1) / EPB)           // 1563 edge-tiles
#define BPC 256                              // blocks per chunk in B passes

typedef _Float16 half8 __attribute__((ext_vector_type(8)));
typedef float f32x4 __attribute__((ext_vector_type(4)));

__device__ __forceinline__ float fatomic_add(float* p, float v) {
    return unsafeAtomicAdd(p, v);   // native global_atomic_add_f32
}

// deg=1 (self loop), pooled=0, sums=0, Wh = fp16(W)
__global__ void k_init(int* __restrict__ deg, float* __restrict__ pooled,
                       float* __restrict__ sums, const float* __restrict__ Wg,
                       __half* __restrict__ Wh) {
    int i = blockIdx.x * blockDim.x + threadIdx.x;
    if (i < NN) deg[i] = 1;
    if (i < NG * F) pooled[i] = 0.f;
    if (i < 2 * F) sums[i] = 0.f;
    if (i < F * F) Wh[i] = __float2half(Wg[i]);
}

// A1: per-(tile, chunk) histogram
__global__ __launch_bounds__(256) void kA1(const int* __restrict__ dst,
                                           int* __restrict__ cnt) {
    __shared__ int hist[NCH];
    int t = threadIdx.x;
    if (t < NCH) hist[t] = 0;
    __syncthreads();
    int base = blockIdx.x * EPB;
#pragma unroll
    for (int k = 0; k < 4; ++k) {
        int e = base + k * 256 + t;
        if (e < NE) atomicAdd(&hist[dst[e] / NPC], 1);
    }
    __syncthreads();
    if (t < NCH) cnt[t * NBE + blockIdx.x] = hist[t];
}

// A2: exclusive scan of cnt (chunk-major, 8*1563 = 12504 elems), one block
__global__ __launch_bounds__(1024) void kA2(const int* __restrict__ cnt,
                                            int* __restrict__ cscan) {
    __shared__ int sh[1024];
    const int M = NCH * NBE;
    const int C = (M + 1023) / 1024;   // 13
    int t = threadIdx.x;
    int beg = t * C, end = min(beg + C, M);
    int s = 0;
    for (int i = beg; i < end; ++i) s += cnt[i];
    sh[t] = s;
    __syncthreads();
    for (int off = 1; off < 1024; off <<= 1) {
        int u = (t >= off) ? sh[t - off] : 0;
        __syncthreads();
        sh[t] += u;
        __syncthreads();
    }
    int run = (t > 0) ? sh[t - 1] : 0;
    for (int i = beg; i < end; ++i) {
        int v = cnt[i];
        cscan[i] = run;
        run += v;
    }
}

// A3: write (dst,src) into chunk-buckets at exact positions
__global__ __launch_bounds__(256) void kA3(const int* __restrict__ src,
                                           const int* __restrict__ dst,
                                           const int* __restrict__ cscan,
                                           int* __restrict__ bdst,
                                           int* __restrict__ bsrc) {
    __shared__ int hoff[NCH];
    int t = threadIdx.x;
    if (t < NCH) hoff[t] = cscan[t * NBE + blockIdx.x];
    __syncthreads();
    int base = blockIdx.x * EPB;
#pragma unroll
    for (int k = 0; k < 4; ++k) {
        int e = base + k * 256 + t;
        if (e < NE) {
            int d = dst[e], s = src[e];
            int pos = atomicAdd(&hoff[d / NPC], 1);
            bdst[pos] = d;
            bsrc[pos] = s;
        }
    }
}

// B1: chunk-local degree count (atomics + bucket both XCD-local)
__global__ __launch_bounds__(256) void kB1(const int* __restrict__ cscan,
                                           const int* __restrict__ bdst,
                                           int* __restrict__ deg) {
    int ch = blockIdx.x & (NCH - 1);
    int slot = blockIdx.x >> 3;
    int beg = cscan[ch * NBE];
    int endc = (ch < NCH - 1) ? cscan[(ch + 1) * NBE] : NE;
    int e0 = beg + slot * EPB + threadIdx.x;
#pragma unroll
    for (int k = 0; k < 4; ++k) {
        int e = e0 + k * 256;
        if (e < endc) atomicAdd(&deg[bdst[e]], 1);
    }
}

// pass 1: per-block sum of (deg-1); also dinv = deg^-1/2, dn2 = 1/deg
__global__ __launch_bounds__(SCAN_B) void k_scan1(const int* __restrict__ deg,
                                                  int* __restrict__ bsum,
                                                  float* __restrict__ dinv,
                                                  float* __restrict__ dn2) {
    int t = threadIdx.x;
    int i = blockIdx.x * SCAN_B + t;
    int d = (i < NN) ? deg[i] : 1;
    if (i < NN) {
        float df = (float)d;
        float r = rsqrtf(df);
        dinv[i] = r;
        dn2[i] = r * r;
    }
    int v = d - 1;
#pragma unroll
    for (int o = 32; o > 0; o >>= 1) v += __shfl_down(v, o, 64);
    __shared__ int ws[16];
    if ((t & 63) == 0) ws[t >> 6] = v;
    __syncthreads();
    if (t == 0) {
        int s = 0;
#pragma unroll
        for (int k = 0; k < 16; ++k) s += ws[k];
        bsum[blockIdx.x] = s;
    }
}

// pass 2+3: global exclusive offs, cur
__global__ __launch_bounds__(SCAN_B) void k_scan3(const int* __restrict__ deg,
                                                  const int* __restrict__ bsum,
                                                  int* __restrict__ offs,
                                                  int* __restrict__ cur) {
    __shared__ int sh[SCAN_B];
    __shared__ int bsh[128];
    int t = threadIdx.x;
    if (t < 128) bsh[t] = (t < NBLK) ? bsum[t] : 0;
    __syncthreads();
    for (int off = 1; off < 128; off <<= 1) {
        int u = (t < 128 && t >= off) ? bsh[t - off] : 0;
        __syncthreads();
        if (t < 128) bsh[t] += u;
        __syncthreads();
    }
    int bpre = (blockIdx.x > 0) ? bsh[blockIdx.x - 1] : 0;
    int i = blockIdx.x * SCAN_B + t;
    int v = (i < NN) ? deg[i] - 1 : 0;
    sh[t] = v;
    __syncthreads();
    for (int off = 1; off < SCAN_B; off <<= 1) {
        int u = (t >= off) ? sh[t - off] : 0;
        __syncthreads();
        sh[t] += u;
        __syncthreads();
    }
    if (i < NN) {
        int o = bpre + sh[t] - v;
        offs[i] = o;
        cur[i] = o;
    }
    if (blockIdx.x == 0 && t == 0) offs[NN] = NE;
}

// B2: chunk-local positional scatter into csrc
__global__ __launch_bounds__(256) void kB2(const int* __restrict__ cscan,
                                           const int* __restrict__ bdst,
                                           const int* __restrict__ bsrc,
                                           int* __restrict__ cur,
                                           int* __restrict__ csrc) {
    int ch = blockIdx.x & (NCH - 1);
    int slot = blockIdx.x >> 3;
    int beg = cscan[ch * NBE];
    int endc = (ch < NCH - 1) ? cscan[(ch + 1) * NBE] : NE;
    int e0 = beg + slot * EPB + threadIdx.x;
#pragma unroll
    for (int k = 0; k < 4; ++k) {
        int e = e0 + k * 256;
        if (e < endc) {
            int pos = atomicAdd(&cur[bdst[e]], 1);
            csrc[pos] = bsrc[e];
        }
    }
}

// u0 = dinv (.) x   (fp32 -> fp16, 2 elems/thread)
__global__ void k_u0(const float2* __restrict__ x2, const float* __restrict__ dinv,
                     __half2* __restrict__ u2) {
    int i = blockIdx.x * blockDim.x + threadIdx.x;   // NN*F/2
    if (i >= NN * F / 2) return;
    float2 v = x2[i];
    float d = dinv[i >> 5];                           // node = (2i)>>6
    u2[i] = __floats2half2_rn(v.x * d, v.y * d);
}

// u_out[n,:] = oscale[n] * (u_in[n,:] + sum_{s in Nin(n)} u_in[s,:])
// wave = 2 nodes: lanes 0-31 -> node 2w, lanes 32-63 -> node 2w+1
__global__ __launch_bounds__(256) void k_hop(const int* __restrict__ offs,
                                             const int* __restrict__ csrc,
                                             const float* __restrict__ oscale,
                                             const __half2* __restrict__ uin,
                                             __half2* __restrict__ uout) {
    int wv = blockIdx.x * 4 + (threadIdx.x >> 6);
    int lane = threadIdx.x & 63;
    int n = wv * 2 + (lane >> 5);      // NN = 12500*4*2 exactly
    int c = lane & 31;
    float2 acc = __half22float2(uin[n * 32 + c]);
    int e = offs[n], end = offs[n + 1];
    for (; e + 8 <= end; e += 8) {
        int s0 = csrc[e],     s1 = csrc[e + 1], s2 = csrc[e + 2], s3 = csrc[e + 3];
        int s4 = csrc[e + 4], s5 = csrc[e + 5], s6 = csrc[e + 6], s7 = csrc[e + 7];
        float2 f0 = __half22float2(uin[s0 * 32 + c]);
        float2 f1 = __half22float2(uin[s1 * 32 + c]);
        float2 f2 = __half22float2(uin[s2 * 32 + c]);
        float2 f3 = __half22float2(uin[s3 * 32 + c]);
        float2 f4 = __half22float2(uin[s4 * 32 + c]);
        float2 f5 = __half22float2(uin[s5 * 32 + c]);
        float2 f6 = __half22float2(uin[s6 * 32 + c]);
        float2 f7 = __half22float2(uin[s7 * 32 + c]);
        acc.x += ((f0.x + f1.x) + (f2.x + f3.x)) + ((f4.x + f5.x) + (f6.x + f7.x));
        acc.y += ((f0.y + f1.y) + (f2.y + f3.y)) + ((f4.y + f5.y) + (f6.y + f7.y));
    }
    for (; e < end; ++e) {
        float2 f = __half22float2(uin[csrc[e] * 32 + c]);
        acc.x += f.x; acc.y += f.y;
    }
    float os = oscale[n];
    uout[n * 32 + c] = __floats2half2_rn(acc.x * os, acc.y * os);
}

// y = relu(h @ Wh^T + b) via MFMA; per-feature sum/sumsq stats
__global__ __launch_bounds__(256) void k_linear(const __half* __restrict__ h,
                                                const __half* __restrict__ Wh,
                                                const float* __restrict__ bg,
                                                __half* __restrict__ y,
                                                float* __restrict__ sums) {
    __shared__ float sred[4][64], qred[4][64];
    int tid = threadIdx.x;
    int wid = tid >> 6, lane = tid & 63;
    int lo = lane & 15, hi = lane >> 4;
    int n0 = blockIdx.x * 64 + wid * 16;

    half8 bf[4][2];
#pragma unroll
    for (int ct = 0; ct < 4; ++ct)
#pragma unroll
        for (int kk = 0; kk < 2; ++kk)
            bf[ct][kk] = *(const half8*)(Wh + (ct * 16 + lo) * 64 + kk * 32 + hi * 8);

    int arow = n0 + lo;
    half8 af[2];
    if (arow < NN) {
        af[0] = *(const half8*)(h + arow * 64 + hi * 8);
        af[1] = *(const half8*)(h + arow * 64 + 32 + hi * 8);
    } else {
#pragma unroll
        for (int j = 0; j < 8; ++j) { af[0][j] = (_Float16)0; af[1][j] = (_Float16)0; }
    }

    f32x4 acc[4];
#pragma unroll
    for (int ct = 0; ct < 4; ++ct) {
        acc[ct] = (f32x4){0.f, 0.f, 0.f, 0.f};
        acc[ct] = __builtin_amdgcn_mfma_f32_16x16x32_f16(af[0], bf[ct][0], acc[ct], 0, 0, 0);
        acc[ct] = __builtin_amdgcn_mfma_f32_16x16x32_f16(af[1], bf[ct][1], acc[ct], 0, 0, 0);
    }

#pragma unroll
    for (int ct = 0; ct < 4; ++ct) {
        int j = ct * 16 + lo;
        float bj = bg[j];
        float ls = 0.f, lq = 0.f;
#pragma unroll
        for (int r = 0; r < 4; ++r) {
            int n = n0 + hi * 4 + r;
            if (n < NN) {
                float v = fmaxf(acc[ct][r] + bj, 0.f);
                y[n * 64 + j] = __float2half(v);
                ls += v; lq += v * v;
            }
        }
        ls += __shfl_xor(ls, 16, 64); ls += __shfl_xor(ls, 32, 64);
        lq += __shfl_xor(lq, 16, 64); lq += __shfl_xor(lq, 32, 64);
        if (hi == 0) { sred[wid][j] = ls; qred[wid][j] = lq; }
    }
    __syncthreads();
    if (tid < 64) {
        float S = sred[0][tid] + sred[1][tid] + sred[2][tid] + sred[3][tid];
        float Q = qred[0][tid] + qred[1][tid] + qred[2][tid] + qred[3][tid];
        fatomic_add(&sums[tid], S);
        fatomic_add(&sums[64 + tid], Q);
    }
}

// BN affine (recomputed per block from sums) + normalize + pooled segment-sum
__global__ __launch_bounds__(256) void k_normpool(const __half* __restrict__ y,
                                                  const int* __restrict__ batch,
                                                  const float* __restrict__ sums,
                                                  const float* __restrict__ gamma,
                                                  const float* __restrict__ beta,
                                                  float* __restrict__ outh,
                                                  float* __restrict__ pooled) {
    int tid = threadIdx.x;
    int j = tid & 63, nl = tid >> 6;
    float mean = sums[j] * (1.0f / NN);
    float var = sums[64 + j] * (1.0f / NN) - mean * mean;
    float rinv = rsqrtf(var + BN_EPS);
    float a = gamma[j] * rinv;
    float c = beta[j] - mean * a;
    int base = blockIdx.x * 256;
    int curg = -1;
    float acc = 0.f;
    for (int it = 0; it < 64; ++it) {
        int n = base + it * 4 + nl;
        if (n >= NN) break;
        int g = batch[n];
        float v = fmaf(__half2float(y[n * 64 + j]), a, c);
        outh[(size_t)n * 64 + j] = v;
        if (g != curg) {
            if (curg >= 0) fatomic_add(&pooled[curg * 64 + j], acc);
            curg = g; acc = 0.f;
        }
        acc += v;
    }
    if (curg >= 0) fatomic_add(&pooled[curg * 64 + j], acc);
}

extern "C" void kernel_launch(void* const* d_in, const int* in_sizes, int n_in,
                              void* d_out, int out_size, void* d_ws, size_t ws_size,
                              hipStream_t stream) {
    const float* x     = (const float*)d_in[0];
    const int*   ei    = (const int*)d_in[1];
    const int*   batch = (const int*)d_in[2];
    const float* W     = (const float*)d_in[3];
    const float* b     = (const float*)d_in[4];
    const float* gamma = (const float*)d_in[5];
    const float* beta  = (const float*)d_in[6];
    const int* src = ei;
    const int* dst = ei + NE;

    float* pooled = (float*)d_out;
    float* outh   = (float*)d_out + NG * F;

    char* w = (char*)d_ws;
    float* dinv  = (float*)w;  w += sizeof(float) * NN;
    float* dn2   = (float*)w;  w += sizeof(float) * NN;
    int*   offs  = (int*)w;    w += sizeof(int) * (NN + 1);
    float* sums  = (float*)w;  w += sizeof(float) * 2 * F;
    int*   bsum  = (int*)w;    w += sizeof(int) * 128;
    __half* Wh   = (__half*)w; w += sizeof(__half) * F * F;
    int*   cnt   = (int*)w;    w += sizeof(int) * NCH * NBE;
    int*   cscan = (int*)w;    w += sizeof(int) * NCH * NBE;
    int*   csrc  = (int*)w;    w += sizeof(int) * NE;
    // union region (25.6 MB = ubufA + ubufB):
    //   ubufA area: bdst+bsrc (12.8 MB, live A3..B2) -> ubufA (u0 onward)
    //   ubufB area: deg+cur   (0.8 MB, live init..B2) -> ubufB (hop1 onward)
    char* uni = w;
    __half* ubufA = (__half*)uni;
    __half* ubufB = (__half*)(uni + sizeof(__half) * NN * F);
    int*    bdst  = (int*)uni;
    int*    bsrc  = bdst + NE;
    int*    deg   = (int*)ubufB;
    int*    cur   = deg + NN;

    const int B = 256;
    dim3 blk(B);

    k_init<<<dim3((NN + B - 1) / B), blk, 0, stream>>>(deg, pooled, sums, W, Wh);
    kA1<<<dim3(NBE), blk, 0, stream>>>(dst, cnt);
    kA2<<<dim3(1), dim3(1024), 0, stream>>>(cnt, cscan);
    kA3<<<dim3(NBE), blk, 0, stream>>>(src, dst, cscan, bdst, bsrc);
    kB1<<<dim3(NCH * BPC), blk, 0, stream>>>(cscan, bdst, deg);
    k_scan1<<<dim3(NBLK), dim3(SCAN_B), 0, stream>>>(deg, bsum, dinv, dn2);
    k_scan3<<<dim3(NBLK), dim3(SCAN_B), 0, stream>>>(deg, bsum, offs, cur);
    kB2<<<dim3(NCH * BPC), blk, 0, stream>>>(cscan, bdst, bsrc, cur, csrc);

    // u0 = dinv.x -> ubufA  (bdst/bsrc dead from here on)
    k_u0<<<dim3((NN * F / 2 + B - 1) / B), blk, 0, stream>>>((const float2*)x, dinv, (__half2*)ubufA);

    dim3 gh(NN / 8);   // 12500 blocks, 4 waves/block, 2 nodes/wave
    k_hop<<<gh, blk, 0, stream>>>(offs, csrc, dn2,  (const __half2*)ubufA, (__half2*)ubufB);
    k_hop<<<gh, blk, 0, stream>>>(offs, csrc, dn2,  (const __half2*)ubufB, (__half2*)ubufA);
    k_hop<<<gh, blk, 0, stream>>>(offs, csrc, dinv, (const __half2*)ubufA, (__half2*)ubufB);

    // linear + relu + BN stats (MFMA): ubufB(h) -> y in ubufA
    __half* yh = ubufA;
    k_linear<<<dim3((NN + 63) / 64), blk, 0, stream>>>(ubufB, Wh, b, yh, sums);
    k_normpool<<<dim3((NN + 255) / 256), blk, 0, stream>>>(yh, batch, sums, gamma, beta, outh, pooled);
}

// Round 9
// 307.921 us; speedup vs baseline: 1.3962x; 1.3962x over previous
//
#include <hip/hip_runtime.h>
#include <hip/hip_fp16.h>

#define NN 100000
#define NE 1600000
#define F 64
#define NG 64
#define BN_EPS 1e-5f
#define EPB 8192
#define NT ((NE + EPB - 1) / EPB)          // 196 edge-tiles
#define NPB 128                             // nodes per bucket (dst>>7)
#define NBKT ((NN + NPB - 1) / NPB)         // 782 buckets
#define M_CNT (NBKT * NT)                   // 153272 counters
#define NSB ((M_CNT + 1023) / 1024)         // 150 scan blocks
#define CAP 3072                            // max edges per bucket (mean 2048, +22 sigma)

typedef _Float16 half8 __attribute__((ext_vector_type(8)));
typedef float f32x4 __attribute__((ext_vector_type(4)));

__device__ __forceinline__ float fatomic_add(float* p, float v) {
    return unsafeAtomicAdd(p, v);   // native global_atomic_add_f32
}

// pooled=0, sums=0, Wh = fp16(W)
__global__ void k_init(float* __restrict__ pooled, float* __restrict__ sums,
                       const float* __restrict__ Wg, __half* __restrict__ Wh) {
    int i = blockIdx.x * blockDim.x + threadIdx.x;
    if (i < NG * F) pooled[i] = 0.f;
    if (i < 2 * F) sums[i] = 0.f;
    if (i < F * F) Wh[i] = __float2half(Wg[i]);
}

// A1: per-tile histogram over 782 node-buckets
__global__ __launch_bounds__(256) void kA1(const int* __restrict__ dst,
                                           int* __restrict__ cnt) {
    __shared__ int hist[NBKT];
    int t = threadIdx.x;
    for (int i = t; i < NBKT; i += 256) hist[i] = 0;
    __syncthreads();
    int base = blockIdx.x * EPB;
#pragma unroll
    for (int r = 0; r < EPB / 256; ++r) {
        int e = base + r * 256 + t;
        if (e < NE) atomicAdd(&hist[dst[e] >> 7], 1);
    }
    __syncthreads();
    for (int i = t; i < NBKT; i += 256)
        cnt[i * NT + blockIdx.x] = hist[i];   // bucket-major layout for the scan
}

// S1: per-1024-chunk partial sums of cnt
__global__ __launch_bounds__(1024) void kS1(const int* __restrict__ cnt,
                                            int* __restrict__ part) {
    int t = threadIdx.x;
    int i = blockIdx.x * 1024 + t;
    int v = (i < M_CNT) ? cnt[i] : 0;
#pragma unroll
    for (int o = 32; o > 0; o >>= 1) v += __shfl_down(v, o, 64);
    __shared__ int ws[16];
    if ((t & 63) == 0) ws[t >> 6] = v;
    __syncthreads();
    if (t == 0) {
        int s = 0;
#pragma unroll
        for (int k = 0; k < 16; ++k) s += ws[k];
        part[blockIdx.x] = s;
    }
}

// S2: exclusive scan of the 150 partials (in place)
__global__ __launch_bounds__(256) void kS2(int* __restrict__ part) {
    __shared__ int sh[256];
    int t = threadIdx.x;
    int v = (t < NSB) ? part[t] : 0;
    sh[t] = v;
    __syncthreads();
    for (int o = 1; o < 256; o <<= 1) {
        int u = (t >= o) ? sh[t - o] : 0;
        __syncthreads();
        sh[t] += u;
        __syncthreads();
    }
    if (t < NSB) part[t] = sh[t] - v;
}

// S3: local scan + partial offset -> cscan (global exclusive scan of cnt)
__global__ __launch_bounds__(1024) void kS3(const int* __restrict__ cnt,
                                            const int* __restrict__ part,
                                            int* __restrict__ cscan) {
    __shared__ int sh[1024];
    int t = threadIdx.x;
    int i = blockIdx.x * 1024 + t;
    int v = (i < M_CNT) ? cnt[i] : 0;
    sh[t] = v;
    __syncthreads();
    for (int o = 1; o < 1024; o <<= 1) {
        int u = (t >= o) ? sh[t - o] : 0;
        __syncthreads();
        sh[t] += u;
        __syncthreads();
    }
    if (i < M_CNT) cscan[i] = part[blockIdx.x] + sh[t] - v;
}

// A3: scatter (dst,src) pairs into bucket runs (contiguous per (tile,bucket))
__global__ __launch_bounds__(256) void kA3(const int* __restrict__ src,
                                           const int* __restrict__ dst,
                                           const int* __restrict__ cscan,
                                           int2* __restrict__ pairs) {
    __shared__ int hoff[NBKT];
    int t = threadIdx.x;
    for (int i = t; i < NBKT; i += 256) hoff[i] = cscan[i * NT + blockIdx.x];
    __syncthreads();
    int base = blockIdx.x * EPB;
#pragma unroll
    for (int r = 0; r < EPB / 256; ++r) {
        int e = base + r * 256 + t;
        if (e < NE) {
            int d = dst[e], s = src[e];
            int pos = atomicAdd(&hoff[d >> 7], 1);
            pairs[pos] = make_int2(d, s);
        }
    }
}

// B2: per-bucket LDS counting sort -> csrc stream + offs/dinv/dn2 (no global atomics)
__global__ __launch_bounds__(256) void kB2(const int2* __restrict__ pairs,
                                           const int* __restrict__ cscan,
                                           int* __restrict__ csrc,
                                           int* __restrict__ offs,
                                           float* __restrict__ dinv,
                                           float* __restrict__ dn2) {
    __shared__ int ld[CAP], ls[CAP], lo[CAP];
    __shared__ int hist[NPB], pre[NPB], curl[NPB];
    int b = blockIdx.x, t = threadIdx.x;
    int s = cscan[b * NT];
    int e = (b == NBKT - 1) ? NE : cscan[(b + 1) * NT];
    int cnt = min(e - s, CAP);
    int nbase = b * NPB;
    if (t < NPB) hist[t] = 0;
    __syncthreads();
    for (int i = t; i < cnt; i += 256) {
        int2 p = pairs[s + i];
        int dl = p.x - nbase;
        ld[i] = dl; ls[i] = p.y;
        atomicAdd(&hist[dl], 1);
    }
    __syncthreads();
    int dg = (t < NPB) ? hist[t] : 0;
    if (t < NPB) pre[t] = dg;
    __syncthreads();
    for (int o = 1; o < NPB; o <<= 1) {
        int u = (t < NPB && t >= o) ? pre[t - o] : 0;
        __syncthreads();
        if (t < NPB) pre[t] += u;
        __syncthreads();
    }
    if (t < NPB) {
        int ex = pre[t] - dg;          // exclusive local prefix
        curl[t] = ex;
        int n = nbase + t;
        if (n < NN) {
            offs[n] = s + ex;
            float r = rsqrtf((float)(dg + 1));   // deg = in-edges + self loop
            dinv[n] = r;
            dn2[n] = r * r;
        }
    }
    if (b == 0 && t == 0) offs[NN] = NE;
    __syncthreads();
    for (int i = t; i < cnt; i += 256) {
        int pos = atomicAdd(&curl[ld[i]], 1);    // LDS atomic only
        lo[pos] = ls[i];
    }
    __syncthreads();
    for (int i = t; i < cnt; i += 256) csrc[s + i] = lo[i];   // full-line stream
}

// u0 = dinv (.) x   (fp32 -> fp16, 2 elems/thread)
__global__ void k_u0(const float2* __restrict__ x2, const float* __restrict__ dinv,
                     __half2* __restrict__ u2) {
    int i = blockIdx.x * blockDim.x + threadIdx.x;   // NN*F/2
    if (i >= NN * F / 2) return;
    float2 v = x2[i];
    float d = dinv[i >> 5];
    u2[i] = __floats2half2_rn(v.x * d, v.y * d);
}

// u_out[n,:] = oscale[n] * (u_in[n,:] + sum_{s in Nin(n)} u_in[s,:])
// wave = 2 nodes: lanes 0-31 -> node 2w, lanes 32-63 -> node 2w+1
__global__ __launch_bounds__(256) void k_hop(const int* __restrict__ offs,
                                             const int* __restrict__ csrc,
                                             const float* __restrict__ oscale,
                                             const __half2* __restrict__ uin,
                                             __half2* __restrict__ uout) {
    int wv = blockIdx.x * 4 + (threadIdx.x >> 6);
    int lane = threadIdx.x & 63;
    int n = wv * 2 + (lane >> 5);      // NN = 12500*4*2 exactly
    int c = lane & 31;
    float2 acc = __half22float2(uin[n * 32 + c]);
    int e = offs[n], end = offs[n + 1];
    for (; e + 8 <= end; e += 8) {
        int s0 = csrc[e],     s1 = csrc[e + 1], s2 = csrc[e + 2], s3 = csrc[e + 3];
        int s4 = csrc[e + 4], s5 = csrc[e + 5], s6 = csrc[e + 6], s7 = csrc[e + 7];
        float2 f0 = __half22float2(uin[s0 * 32 + c]);
        float2 f1 = __half22float2(uin[s1 * 32 + c]);
        float2 f2 = __half22float2(uin[s2 * 32 + c]);
        float2 f3 = __half22float2(uin[s3 * 32 + c]);
        float2 f4 = __half22float2(uin[s4 * 32 + c]);
        float2 f5 = __half22float2(uin[s5 * 32 + c]);
        float2 f6 = __half22float2(uin[s6 * 32 + c]);
        float2 f7 = __half22float2(uin[s7 * 32 + c]);
        acc.x += ((f0.x + f1.x) + (f2.x + f3.x)) + ((f4.x + f5.x) + (f6.x + f7.x));
        acc.y += ((f0.y + f1.y) + (f2.y + f3.y)) + ((f4.y + f5.y) + (f6.y + f7.y));
    }
    for (; e < end; ++e) {
        float2 f = __half22float2(uin[csrc[e] * 32 + c]);
        acc.x += f.x; acc.y += f.y;
    }
    float os = oscale[n];
    uout[n * 32 + c] = __floats2half2_rn(acc.x * os, acc.y * os);
}

// y = relu(h @ Wh^T + b) via MFMA; per-feature sum/sumsq stats
__global__ __launch_bounds__(256) void k_linear(const __half* __restrict__ h,
                                                const __half* __restrict__ Wh,
                                                const float* __restrict__ bg,
                                                __half* __restrict__ y,
                                                float* __restrict__ sums) {
    __shared__ float sred[4][64], qred[4][64];
    int tid = threadIdx.x;
    int wid = tid >> 6, lane = tid & 63;
    int lo = lane & 15, hi = lane >> 4;
    int n0 = blockIdx.x * 64 + wid * 16;

    half8 bf[4][2];
#pragma unroll
    for (int ct = 0; ct < 4; ++ct)
#pragma unroll
        for (int kk = 0; kk < 2; ++kk)
            bf[ct][kk] = *(const half8*)(Wh + (ct * 16 + lo) * 64 + kk * 32 + hi * 8);

    int arow = n0 + lo;
    half8 af[2];
    if (arow < NN) {
        af[0] = *(const half8*)(h + arow * 64 + hi * 8);
        af[1] = *(const half8*)(h + arow * 64 + 32 + hi * 8);
    } else {
#pragma unroll
        for (int j = 0; j < 8; ++j) { af[0][j] = (_Float16)0; af[1][j] = (_Float16)0; }
    }

    f32x4 acc[4];
#pragma unroll
    for (int ct = 0; ct < 4; ++ct) {
        acc[ct] = (f32x4){0.f, 0.f, 0.f, 0.f};
        acc[ct] = __builtin_amdgcn_mfma_f32_16x16x32_f16(af[0], bf[ct][0], acc[ct], 0, 0, 0);
        acc[ct] = __builtin_amdgcn_mfma_f32_16x16x32_f16(af[1], bf[ct][1], acc[ct], 0, 0, 0);
    }

#pragma unroll
    for (int ct = 0; ct < 4; ++ct) {
        int j = ct * 16 + lo;
        float bj = bg[j];
        float ls = 0.f, lq = 0.f;
#pragma unroll
        for (int r = 0; r < 4; ++r) {
            int n = n0 + hi * 4 + r;
            if (n < NN) {
                float v = fmaxf(acc[ct][r] + bj, 0.f);
                y[n * 64 + j] = __float2half(v);
                ls += v; lq += v * v;
            }
        }
        ls += __shfl_xor(ls, 16, 64); ls += __shfl_xor(ls, 32, 64);
        lq += __shfl_xor(lq, 16, 64); lq += __shfl_xor(lq, 32, 64);
        if (hi == 0) { sred[wid][j] = ls; qred[wid][j] = lq; }
    }
    __syncthreads();
    if (tid < 64) {
        float S = sred[0][tid] + sred[1][tid] + sred[2][tid] + sred[3][tid];
        float Q = qred[0][tid] + qred[1][tid] + qred[2][tid] + qred[3][tid];
        fatomic_add(&sums[tid], S);
        fatomic_add(&sums[64 + tid], Q);
    }
}

// BN affine (recomputed per block from sums) + normalize + pooled segment-sum
__global__ __launch_bounds__(256) void k_normpool(const __half* __restrict__ y,
                                                  const int* __restrict__ batch,
                                                  const float* __restrict__ sums,
                                                  const float* __restrict__ gamma,
                                                  const float* __restrict__ beta,
                                                  float* __restrict__ outh,
                                                  float* __restrict__ pooled) {
    int tid = threadIdx.x;
    int j = tid & 63, nl = tid >> 6;
    float mean = sums[j] * (1.0f / NN);
    float var = sums[64 + j] * (1.0f / NN) - mean * mean;
    float rinv = rsqrtf(var + BN_EPS);
    float a = gamma[j] * rinv;
    float c = beta[j] - mean * a;
    int base = blockIdx.x * 256;
    int curg = -1;
    float acc = 0.f;
    for (int it = 0; it < 64; ++it) {
        int n = base + it * 4 + nl;
        if (n >= NN) break;
        int g = batch[n];
        float v = fmaf(__half2float(y[n * 64 + j]), a, c);
        outh[(size_t)n * 64 + j] = v;
        if (g != curg) {
            if (curg >= 0) fatomic_add(&pooled[curg * 64 + j], acc);
            curg = g; acc = 0.f;
        }
        acc += v;
    }
    if (curg >= 0) fatomic_add(&pooled[curg * 64 + j], acc);
}

extern "C" void kernel_launch(void* const* d_in, const int* in_sizes, int n_in,
                              void* d_out, int out_size, void* d_ws, size_t ws_size,
                              hipStream_t stream) {
    const float* x     = (const float*)d_in[0];
    const int*   ei    = (const int*)d_in[1];
    const int*   batch = (const int*)d_in[2];
    const float* W     = (const float*)d_in[3];
    const float* b     = (const float*)d_in[4];
    const float* gamma = (const float*)d_in[5];
    const float* beta  = (const float*)d_in[6];
    const int* src = ei;
    const int* dst = ei + NE;

    float* pooled = (float*)d_out;
    float* outh   = (float*)d_out + NG * F;

    char* w = (char*)d_ws;
    float* dinv  = (float*)w;  w += sizeof(float) * NN;
    float* dn2   = (float*)w;  w += sizeof(float) * NN;
    int*   offs  = (int*)w;    w += sizeof(int) * (NN + 1);
    float* sums  = (float*)w;  w += sizeof(float) * 2 * F;
    __half* Wh   = (__half*)w; w += sizeof(__half) * F * F;
    int*   cnt   = (int*)w;    w += sizeof(int) * M_CNT;
    int*   cscan = (int*)w;    w += sizeof(int) * M_CNT;
    int*   part  = (int*)w;    w += sizeof(int) * 256;
    int*   csrc  = (int*)w;    w += sizeof(int) * NE;
    // union region (25.6 MB): pairs (12.8 MB, live A3..B2) -> ubufA (u0 onward)
    char* uni = w;
    __half* ubufA = (__half*)uni;
    __half* ubufB = (__half*)(uni + sizeof(__half) * NN * F);
    int2*   pairs = (int2*)uni;

    const int B = 256;
    dim3 blk(B);

    k_init<<<dim3((NN + B - 1) / B), blk, 0, stream>>>(pooled, sums, W, Wh);
    kA1<<<dim3(NT), blk, 0, stream>>>(dst, cnt);
    kS1<<<dim3(NSB), dim3(1024), 0, stream>>>(cnt, part);
    kS2<<<dim3(1), blk, 0, stream>>>(part);
    kS3<<<dim3(NSB), dim3(1024), 0, stream>>>(cnt, part, cscan);
    kA3<<<dim3(NT), blk, 0, stream>>>(src, dst, cscan, pairs);
    kB2<<<dim3(NBKT), blk, 0, stream>>>(pairs, cscan, csrc, offs, dinv, dn2);

    // u0 = dinv.x -> ubufA  (pairs dead from here on)
    k_u0<<<dim3((NN * F / 2 + B - 1) / B), blk, 0, stream>>>((const float2*)x, dinv, (__half2*)ubufA);

    dim3 gh(NN / 8);   // 12500 blocks, 4 waves/block, 2 nodes/wave
    k_hop<<<gh, blk, 0, stream>>>(offs, csrc, dn2,  (const __half2*)ubufA, (__half2*)ubufB);
    k_hop<<<gh, blk, 0, stream>>>(offs, csrc, dn2,  (const __half2*)ubufB, (__half2*)ubufA);
    k_hop<<<gh, blk, 0, stream>>>(offs, csrc, dinv, (const __half2*)ubufA, (__half2*)ubufB);

    // linear + relu + BN stats (MFMA): ubufB(h) -> y in ubufA
    __half* yh = ubufA;
    k_linear<<<dim3((NN + 63) / 64), blk, 0, stream>>>(ubufB, Wh, b, yh, sums);
    k_normpool<<<dim3((NN + 255) / 256), blk, 0, stream>>>(yh, batch, sums, gamma, beta, outh, pooled);
}

// Round 10
// 278.174 us; speedup vs baseline: 1.5455x; 1.1069x over previous
//
#include <hip/hip_runtime.h>
#include <hip/hip_fp16.h>

#define NN 100000
#define NE 1600000
#define F 64
#define NG 64
#define BN_EPS 1e-5f
#define EPB 8192
#define NT ((NE + EPB - 1) / EPB)          // 196 edge-tiles
#define NPB 128                             // nodes per bucket (dst>>7)
#define NBKT ((NN + NPB - 1) / NPB)         // 782 buckets
#define M_CNT (NBKT * NT)                   // 153272 counters
#define NSB ((M_CNT + 1023) / 1024)         // 150 scan blocks
#define CAP 3072                            // max edges per bucket (mean 2048, +22 sigma)
#define NLB ((NN + 63) / 64)                // 1563 linear blocks
#define RED_B 16                            // reduction blocks
#define RPB ((NLB + RED_B - 1) / RED_B)     // 98 rows per reduction block

typedef _Float16 half8 __attribute__((ext_vector_type(8)));
typedef float f32x4 __attribute__((ext_vector_type(4)));

__device__ __forceinline__ float fatomic_add(float* p, float v) {
    return unsafeAtomicAdd(p, v);   // native global_atomic_add_f32
}

// pooled=0, sums=0, Wh = fp16(W)
__global__ void k_init(float* __restrict__ pooled, float* __restrict__ sums,
                       const float* __restrict__ Wg, __half* __restrict__ Wh) {
    int i = blockIdx.x * blockDim.x + threadIdx.x;
    if (i < NG * F) pooled[i] = 0.f;
    if (i < 2 * F) sums[i] = 0.f;
    if (i < F * F) Wh[i] = __float2half(Wg[i]);
}

// A1: per-tile histogram over 782 node-buckets
__global__ __launch_bounds__(256) void kA1(const int* __restrict__ dst,
                                           int* __restrict__ cnt) {
    __shared__ int hist[NBKT];
    int t = threadIdx.x;
    for (int i = t; i < NBKT; i += 256) hist[i] = 0;
    __syncthreads();
    int base = blockIdx.x * EPB;
#pragma unroll
    for (int r = 0; r < EPB / 256; ++r) {
        int e = base + r * 256 + t;
        if (e < NE) atomicAdd(&hist[dst[e] >> 7], 1);
    }
    __syncthreads();
    for (int i = t; i < NBKT; i += 256)
        cnt[i * NT + blockIdx.x] = hist[i];   // bucket-major layout for the scan
}

// S1: per-1024-chunk partial sums of cnt
__global__ __launch_bounds__(1024) void kS1(const int* __restrict__ cnt,
                                            int* __restrict__ part) {
    int t = threadIdx.x;
    int i = blockIdx.x * 1024 + t;
    int v = (i < M_CNT) ? cnt[i] : 0;
#pragma unroll
    for (int o = 32; o > 0; o >>= 1) v += __shfl_down(v, o, 64);
    __shared__ int ws[16];
    if ((t & 63) == 0) ws[t >> 6] = v;
    __syncthreads();
    if (t == 0) {
        int s = 0;
#pragma unroll
        for (int k = 0; k < 16; ++k) s += ws[k];
        part[blockIdx.x] = s;
    }
}

// S2: exclusive scan of the 150 partials (in place)
__global__ __launch_bounds__(256) void kS2(int* __restrict__ part) {
    __shared__ int sh[256];
    int t = threadIdx.x;
    int v = (t < NSB) ? part[t] : 0;
    sh[t] = v;
    __syncthreads();
    for (int o = 1; o < 256; o <<= 1) {
        int u = (t >= o) ? sh[t - o] : 0;
        __syncthreads();
        sh[t] += u;
        __syncthreads();
    }
    if (t < NSB) part[t] = sh[t] - v;
}

// S3: local scan + partial offset -> cscan (global exclusive scan of cnt)
__global__ __launch_bounds__(1024) void kS3(const int* __restrict__ cnt,
                                            const int* __restrict__ part,
                                            int* __restrict__ cscan) {
    __shared__ int sh[1024];
    int t = threadIdx.x;
    int i = blockIdx.x * 1024 + t;
    int v = (i < M_CNT) ? cnt[i] : 0;
    sh[t] = v;
    __syncthreads();
    for (int o = 1; o < 1024; o <<= 1) {
        int u = (t >= o) ? sh[t - o] : 0;
        __syncthreads();
        sh[t] += u;
        __syncthreads();
    }
    if (i < M_CNT) cscan[i] = part[blockIdx.x] + sh[t] - v;
}

// A3: scatter (dst,src) pairs into bucket runs (contiguous per (tile,bucket))
__global__ __launch_bounds__(256) void kA3(const int* __restrict__ src,
                                           const int* __restrict__ dst,
                                           const int* __restrict__ cscan,
                                           int2* __restrict__ pairs) {
    __shared__ int hoff[NBKT];
    int t = threadIdx.x;
    for (int i = t; i < NBKT; i += 256) hoff[i] = cscan[i * NT + blockIdx.x];
    __syncthreads();
    int base = blockIdx.x * EPB;
#pragma unroll
    for (int r = 0; r < EPB / 256; ++r) {
        int e = base + r * 256 + t;
        if (e < NE) {
            int d = dst[e], s = src[e];
            int pos = atomicAdd(&hoff[d >> 7], 1);
            pairs[pos] = make_int2(d, s);
        }
    }
}

// B2: per-bucket LDS counting sort -> csrc stream + offs/dinv/dn2 (no global atomics)
__global__ __launch_bounds__(256) void kB2(const int2* __restrict__ pairs,
                                           const int* __restrict__ cscan,
                                           int* __restrict__ csrc,
                                           int* __restrict__ offs,
                                           float* __restrict__ dinv,
                                           float* __restrict__ dn2) {
    __shared__ int ld[CAP], ls[CAP], lo[CAP];
    __shared__ int hist[NPB], pre[NPB], curl[NPB];
    int b = blockIdx.x, t = threadIdx.x;
    int s = cscan[b * NT];
    int e = (b == NBKT - 1) ? NE : cscan[(b + 1) * NT];
    int cnt = min(e - s, CAP);
    int nbase = b * NPB;
    if (t < NPB) hist[t] = 0;
    __syncthreads();
    for (int i = t; i < cnt; i += 256) {
        int2 p = pairs[s + i];
        int dl = p.x - nbase;
        ld[i] = dl; ls[i] = p.y;
        atomicAdd(&hist[dl], 1);
    }
    __syncthreads();
    int dg = (t < NPB) ? hist[t] : 0;
    if (t < NPB) pre[t] = dg;
    __syncthreads();
    for (int o = 1; o < NPB; o <<= 1) {
        int u = (t < NPB && t >= o) ? pre[t - o] : 0;
        __syncthreads();
        if (t < NPB) pre[t] += u;
        __syncthreads();
    }
    if (t < NPB) {
        int ex = pre[t] - dg;          // exclusive local prefix
        curl[t] = ex;
        int n = nbase + t;
        if (n < NN) {
            offs[n] = s + ex;
            float r = rsqrtf((float)(dg + 1));   // deg = in-edges + self loop
            dinv[n] = r;
            dn2[n] = r * r;
        }
    }
    if (b == 0 && t == 0) offs[NN] = NE;
    __syncthreads();
    for (int i = t; i < cnt; i += 256) {
        int pos = atomicAdd(&curl[ld[i]], 1);    // LDS atomic only
        lo[pos] = ls[i];
    }
    __syncthreads();
    for (int i = t; i < cnt; i += 256) csrc[s + i] = lo[i];   // full-line stream
}

// u0 = dinv (.) x   (fp32 -> fp16, 2 elems/thread)
__global__ void k_u0(const float2* __restrict__ x2, const float* __restrict__ dinv,
                     __half2* __restrict__ u2) {
    int i = blockIdx.x * blockDim.x + threadIdx.x;   // NN*F/2
    if (i >= NN * F / 2) return;
    float2 v = x2[i];
    float d = dinv[i >> 5];
    u2[i] = __floats2half2_rn(v.x * d, v.y * d);
}

// u_out[n,:] = oscale[n] * (u_in[n,:] + sum_{s in Nin(n)} u_in[s,:])
// wave = 2 nodes: lanes 0-31 -> node 2w, lanes 32-63 -> node 2w+1
__global__ __launch_bounds__(256) void k_hop(const int* __restrict__ offs,
                                             const int* __restrict__ csrc,
                                             const float* __restrict__ oscale,
                                             const __half2* __restrict__ uin,
                                             __half2* __restrict__ uout) {
    int wv = blockIdx.x * 4 + (threadIdx.x >> 6);
    int lane = threadIdx.x & 63;
    int n = wv * 2 + (lane >> 5);      // NN = 12500*4*2 exactly
    int c = lane & 31;
    float2 acc = __half22float2(uin[n * 32 + c]);
    int e = offs[n], end = offs[n + 1];
    for (; e + 8 <= end; e += 8) {
        int s0 = csrc[e],     s1 = csrc[e + 1], s2 = csrc[e + 2], s3 = csrc[e + 3];
        int s4 = csrc[e + 4], s5 = csrc[e + 5], s6 = csrc[e + 6], s7 = csrc[e + 7];
        float2 f0 = __half22float2(uin[s0 * 32 + c]);
        float2 f1 = __half22float2(uin[s1 * 32 + c]);
        float2 f2 = __half22float2(uin[s2 * 32 + c]);
        float2 f3 = __half22float2(uin[s3 * 32 + c]);
        float2 f4 = __half22float2(uin[s4 * 32 + c]);
        float2 f5 = __half22float2(uin[s5 * 32 + c]);
        float2 f6 = __half22float2(uin[s6 * 32 + c]);
        float2 f7 = __half22float2(uin[s7 * 32 + c]);
        acc.x += ((f0.x + f1.x) + (f2.x + f3.x)) + ((f4.x + f5.x) + (f6.x + f7.x));
        acc.y += ((f0.y + f1.y) + (f2.y + f3.y)) + ((f4.y + f5.y) + (f6.y + f7.y));
    }
    for (; e < end; ++e) {
        float2 f = __half22float2(uin[csrc[e] * 32 + c]);
        acc.x += f.x; acc.y += f.y;
    }
    float os = oscale[n];
    uout[n * 32 + c] = __floats2half2_rn(acc.x * os, acc.y * os);
}

// y = relu(h @ Wh^T + b) via MFMA; per-block partial stats -> psum (NO atomics)
__global__ __launch_bounds__(256) void k_linear(const __half* __restrict__ h,
                                                const __half* __restrict__ Wh,
                                                const float* __restrict__ bg,
                                                __half* __restrict__ y,
                                                float* __restrict__ psum) {
    __shared__ float sred[4][64], qred[4][64];
    int tid = threadIdx.x;
    int wid = tid >> 6, lane = tid & 63;
    int lo = lane & 15, hi = lane >> 4;
    int n0 = blockIdx.x * 64 + wid * 16;

    half8 bf[4][2];
#pragma unroll
    for (int ct = 0; ct < 4; ++ct)
#pragma unroll
        for (int kk = 0; kk < 2; ++kk)
            bf[ct][kk] = *(const half8*)(Wh + (ct * 16 + lo) * 64 + kk * 32 + hi * 8);

    int arow = n0 + lo;
    half8 af[2];
    if (arow < NN) {
        af[0] = *(const half8*)(h + arow * 64 + hi * 8);
        af[1] = *(const half8*)(h + arow * 64 + 32 + hi * 8);
    } else {
#pragma unroll
        for (int j = 0; j < 8; ++j) { af[0][j] = (_Float16)0; af[1][j] = (_Float16)0; }
    }

    f32x4 acc[4];
#pragma unroll
    for (int ct = 0; ct < 4; ++ct) {
        acc[ct] = (f32x4){0.f, 0.f, 0.f, 0.f};
        acc[ct] = __builtin_amdgcn_mfma_f32_16x16x32_f16(af[0], bf[ct][0], acc[ct], 0, 0, 0);
        acc[ct] = __builtin_amdgcn_mfma_f32_16x16x32_f16(af[1], bf[ct][1], acc[ct], 0, 0, 0);
    }

#pragma unroll
    for (int ct = 0; ct < 4; ++ct) {
        int j = ct * 16 + lo;
        float bj = bg[j];
        float ls = 0.f, lq = 0.f;
#pragma unroll
        for (int r = 0; r < 4; ++r) {
            int n = n0 + hi * 4 + r;
            if (n < NN) {
                float v = fmaxf(acc[ct][r] + bj, 0.f);
                y[n * 64 + j] = __float2half(v);
                ls += v; lq += v * v;
            }
        }
        ls += __shfl_xor(ls, 16, 64); ls += __shfl_xor(ls, 32, 64);
        lq += __shfl_xor(lq, 16, 64); lq += __shfl_xor(lq, 32, 64);
        if (hi == 0) { sred[wid][j] = ls; qred[wid][j] = lq; }
    }
    __syncthreads();
    if (tid < 128) {
        int c = tid & 63;
        float v = (tid < 64)
            ? (sred[0][c] + sred[1][c] + sred[2][c] + sred[3][c])
            : (qred[0][c] + qred[1][c] + qred[2][c] + qred[3][c]);
        psum[blockIdx.x * 128 + tid] = v;    // streaming full-line write
    }
}

// reduce psum[NLB][128] -> sums[128]; only 16*128 spread-out atomics
__global__ __launch_bounds__(256) void k_red(const float* __restrict__ psum,
                                             float* __restrict__ sums) {
    int t = threadIdx.x;
    int c = t & 127, half = t >> 7;           // 2 threads per column
    int r0 = blockIdx.x * RPB + half;
    int r1 = min((int)(blockIdx.x + 1) * RPB, NLB);
    float s = 0.f;
    for (int r = r0; r < r1; r += 2)
        s += psum[r * 128 + c];
    __shared__ float sh[128];
    if (half == 0) sh[c] = s;
    __syncthreads();
    if (half == 1) {
        float v = s + sh[c];
        fatomic_add(&sums[c], v);
    }
}

// BN affine (recomputed per block from sums) + normalize + pooled segment-sum
__global__ __launch_bounds__(256) void k_normpool(const __half* __restrict__ y,
                                                  const int* __restrict__ batch,
                                                  const float* __restrict__ sums,
                                                  const float* __restrict__ gamma,
                                                  const float* __restrict__ beta,
                                                  float* __restrict__ outh,
                                                  float* __restrict__ pooled) {
    int tid = threadIdx.x;
    int j = tid & 63, nl = tid >> 6;
    float mean = sums[j] * (1.0f / NN);
    float var = sums[64 + j] * (1.0f / NN) - mean * mean;
    float rinv = rsqrtf(var + BN_EPS);
    float a = gamma[j] * rinv;
    float c = beta[j] - mean * a;
    int base = blockIdx.x * 256;
    int curg = -1;
    float acc = 0.f;
    for (int it = 0; it < 64; ++it) {
        int n = base + it * 4 + nl;
        if (n >= NN) break;
        int g = batch[n];
        float v = fmaf(__half2float(y[n * 64 + j]), a, c);
        outh[(size_t)n * 64 + j] = v;
        if (g != curg) {
            if (curg >= 0) fatomic_add(&pooled[curg * 64 + j], acc);
            curg = g; acc = 0.f;
        }
        acc += v;
    }
    if (curg >= 0) fatomic_add(&pooled[curg * 64 + j], acc);
}

extern "C" void kernel_launch(void* const* d_in, const int* in_sizes, int n_in,
                              void* d_out, int out_size, void* d_ws, size_t ws_size,
                              hipStream_t stream) {
    const float* x     = (const float*)d_in[0];
    const int*   ei    = (const int*)d_in[1];
    const int*   batch = (const int*)d_in[2];
    const float* W     = (const float*)d_in[3];
    const float* b     = (const float*)d_in[4];
    const float* gamma = (const float*)d_in[5];
    const float* beta  = (const float*)d_in[6];
    const int* src = ei;
    const int* dst = ei + NE;

    float* pooled = (float*)d_out;
    float* outh   = (float*)d_out + NG * F;

    char* w = (char*)d_ws;
    float* dinv  = (float*)w;  w += sizeof(float) * NN;
    float* dn2   = (float*)w;  w += sizeof(float) * NN;
    int*   offs  = (int*)w;    w += sizeof(int) * (NN + 1);
    float* sums  = (float*)w;  w += sizeof(float) * 2 * F;
    __half* Wh   = (__half*)w; w += sizeof(__half) * F * F;
    float* psum  = (float*)w;  w += sizeof(float) * NLB * 128;
    int*   cnt   = (int*)w;    w += sizeof(int) * M_CNT;
    int*   cscan = (int*)w;    w += sizeof(int) * M_CNT;
    int*   part  = (int*)w;    w += sizeof(int) * 256;
    int*   csrc  = (int*)w;    w += sizeof(int) * NE;
    // union region (25.6 MB): pairs (12.8 MB, live A3..B2) -> ubufA (u0 onward)
    char* uni = w;
    __half* ubufA = (__half*)uni;
    __half* ubufB = (__half*)(uni + sizeof(__half) * NN * F);
    int2*   pairs = (int2*)uni;

    const int B = 256;
    dim3 blk(B);

    k_init<<<dim3((NN + B - 1) / B), blk, 0, stream>>>(pooled, sums, W, Wh);
    kA1<<<dim3(NT), blk, 0, stream>>>(dst, cnt);
    kS1<<<dim3(NSB), dim3(1024), 0, stream>>>(cnt, part);
    kS2<<<dim3(1), blk, 0, stream>>>(part);
    kS3<<<dim3(NSB), dim3(1024), 0, stream>>>(cnt, part, cscan);
    kA3<<<dim3(NT), blk, 0, stream>>>(src, dst, cscan, pairs);
    kB2<<<dim3(NBKT), blk, 0, stream>>>(pairs, cscan, csrc, offs, dinv, dn2);

    // u0 = dinv.x -> ubufA  (pairs dead from here on)
    k_u0<<<dim3((NN * F / 2 + B - 1) / B), blk, 0, stream>>>((const float2*)x, dinv, (__half2*)ubufA);

    dim3 gh(NN / 8);   // 12500 blocks, 4 waves/block, 2 nodes/wave
    k_hop<<<gh, blk, 0, stream>>>(offs, csrc, dn2,  (const __half2*)ubufA, (__half2*)ubufB);
    k_hop<<<gh, blk, 0, stream>>>(offs, csrc, dn2,  (const __half2*)ubufB, (__half2*)ubufA);
    k_hop<<<gh, blk, 0, stream>>>(offs, csrc, dinv, (const __half2*)ubufA, (__half2*)ubufB);

    // linear + relu (MFMA) with contention-free stats: ubufB(h) -> y in ubufA
    __half* yh = ubufA;
    k_linear<<<dim3(NLB), blk, 0, stream>>>(ubufB, Wh, b, yh, psum);
    k_red<<<dim3(RED_B), blk, 0, stream>>>(psum, sums);
    k_normpool<<<dim3((NN + 255) / 256), blk, 0, stream>>>(yh, batch, sums, gamma, beta, outh, pooled);
}